// Round 1
// baseline (522.899 us; speedup 1.0000x reference)
//
#include <hip/hip_runtime.h>
#include <hip/hip_bf16.h>

#define IN_DIM 1024
#define HID_DIM 2048
#define T_DIM 256

typedef __attribute__((ext_vector_type(4))) float floatx4;
typedef __attribute__((ext_vector_type(8))) short shortx8;   // 8 bf16 (4 VGPRs), per guide §3

__device__ __forceinline__ unsigned short f2bf(float f) {
  // round-to-nearest-even fp32 -> bf16
  unsigned u = __builtin_bit_cast(unsigned, f);
  u += 0x7FFFu + ((u >> 16) & 1u);
  return (unsigned short)(u >> 16);
}

__global__ __launch_bounds__(256) void cat_linear_kernel(
    const float* __restrict__ x, const int* __restrict__ cat_ids,
    const float* __restrict__ W, const float* __restrict__ bias,
    float* __restrict__ out) {
  const int nt = blockIdx.x;   // 0..15  (hidden tiles)
  const int mt = blockIdx.y;   // 0..1   (token tiles)
  const int b  = blockIdx.z;   // 0..63  (batch)
  const int tid = threadIdx.x;
  const int c = cat_ids[b];

  const int n0 = nt * 128;
  const float* xb = x + ((size_t)b * T_DIM + (size_t)mt * 128) * IN_DIM;
  const float* Wc = W + (size_t)c * IN_DIM * HID_DIM + n0;

  // A: [m][k] row-major, BK=32 (no pad — m97-proven read pattern)
  __shared__ __attribute__((aligned(16))) unsigned short As[128 * 32];   // 8 KB
  // B: [n][k] (transposed tile), padded to 40 shorts/row (80B, 16B-aligned)
  __shared__ __attribute__((aligned(16))) unsigned short Bs[128 * 40];   // 10 KB

  const int lane = tid & 63;
  const int wv   = tid >> 6;         // wave 0..3 -> 2x2
  const int wm   = (wv >> 1) * 64;
  const int wn   = (wv & 1) * 64;
  const int l16  = lane & 15;
  const int quad = lane >> 4;

  floatx4 acc[4][4] = {};

  const int ar = tid >> 3;           // A stage: row 0..31 (+p*32)
  const int ac = (tid & 7) * 4;      // A stage: k col 0..28
  const int kp = tid >> 4;           // B stage: k-pair 0..15
  const int bn = (tid & 15) * 4;     // B stage: n 0..60 (+q*64)

  for (int ks = 0; ks < IN_DIM / 32; ++ks) {
    const int k0 = ks * 32;

    // ---- stage A: 128x32 fp32 -> bf16 LDS [m][k]
    #pragma unroll
    for (int p = 0; p < 4; ++p) {
      const int m = ar + p * 32;
      const float4 v = *reinterpret_cast<const float4*>(xb + (size_t)m * IN_DIM + k0 + ac);
      ushort4 h;
      h.x = f2bf(v.x); h.y = f2bf(v.y); h.z = f2bf(v.z); h.w = f2bf(v.w);
      *reinterpret_cast<ushort4*>(&As[m * 32 + ac]) = h;
    }

    // ---- stage B: 32x128 fp32 tile of W, transpose -> bf16 LDS [n][k]
    // thread loads rows (2kp, 2kp+1), 4 consecutive n; packs k-pairs -> b32 writes
    #pragma unroll
    for (int q = 0; q < 2; ++q) {
      const int n = bn + q * 64;
      const float4 v0 = *reinterpret_cast<const float4*>(Wc + (size_t)(k0 + 2 * kp)     * HID_DIM + n);
      const float4 v1 = *reinterpret_cast<const float4*>(Wc + (size_t)(k0 + 2 * kp + 1) * HID_DIM + n);
      unsigned w;
      w = (unsigned)f2bf(v0.x) | ((unsigned)f2bf(v1.x) << 16);
      *reinterpret_cast<unsigned*>(&Bs[(n + 0) * 40 + 2 * kp]) = w;
      w = (unsigned)f2bf(v0.y) | ((unsigned)f2bf(v1.y) << 16);
      *reinterpret_cast<unsigned*>(&Bs[(n + 1) * 40 + 2 * kp]) = w;
      w = (unsigned)f2bf(v0.z) | ((unsigned)f2bf(v1.z) << 16);
      *reinterpret_cast<unsigned*>(&Bs[(n + 2) * 40 + 2 * kp]) = w;
      w = (unsigned)f2bf(v0.w) | ((unsigned)f2bf(v1.w) << 16);
      *reinterpret_cast<unsigned*>(&Bs[(n + 3) * 40 + 2 * kp]) = w;
    }

    __syncthreads();

    // ---- fragments: A[m=l16][k=quad*8+j], B[k=quad*8+j][n=l16]
    shortx8 af[4], bfr[4];
    #pragma unroll
    for (int i = 0; i < 4; ++i)
      af[i] = *reinterpret_cast<const shortx8*>(&As[(wm + i * 16 + l16) * 32 + quad * 8]);
    #pragma unroll
    for (int j = 0; j < 4; ++j)
      bfr[j] = *reinterpret_cast<const shortx8*>(&Bs[(wn + j * 16 + l16) * 40 + quad * 8]);

    #pragma unroll
    for (int i = 0; i < 4; ++i) {
      #pragma unroll
      for (int j = 0; j < 4; ++j) {
        acc[i][j] = __builtin_amdgcn_mfma_f32_16x16x32_bf16(af[i], bfr[j], acc[i][j], 0, 0, 0);
      }
    }

    __syncthreads();
  }

  // ---- epilogue: C/D layout col=l16, row=quad*4+r; add bias, fp32 store
  float* outp = out + ((size_t)b * T_DIM + (size_t)mt * 128) * HID_DIM + n0;
  const float* bp = bias + (size_t)c * HID_DIM + n0;
  #pragma unroll
  for (int j = 0; j < 4; ++j) {
    const float bj = bp[wn + j * 16 + l16];
    #pragma unroll
    for (int i = 0; i < 4; ++i) {
      #pragma unroll
      for (int r = 0; r < 4; ++r) {
        const int m = wm + i * 16 + quad * 4 + r;
        outp[(size_t)m * HID_DIM + wn + j * 16 + l16] = acc[i][j][r] + bj;
      }
    }
  }
}

extern "C" void kernel_launch(void* const* d_in, const int* in_sizes, int n_in,
                              void* d_out, int out_size, void* d_ws, size_t ws_size,
                              hipStream_t stream) {
  const float* x    = (const float*)d_in[0];
  const int*   cat  = (const int*)d_in[1];
  const float* W    = (const float*)d_in[2];
  const float* bias = (const float*)d_in[3];
  float* out = (float*)d_out;

  dim3 grid(HID_DIM / 128, T_DIM / 128, 64);   // (16, 2, 64) = 2048 blocks
  hipLaunchKernelGGL(cat_linear_kernel, grid, dim3(256), 0, stream,
                     x, cat, W, bias, out);
}